// Round 9
// baseline (292.561 us; speedup 1.0000x reference)
//
#include <hip/hip_runtime.h>
#include <math.h>

using short8   = __attribute__((ext_vector_type(8)))  short;
using floatx4  = __attribute__((ext_vector_type(4)))  float;
using floatx16 = __attribute__((ext_vector_type(16))) float;
using uintx4   = __attribute__((ext_vector_type(4)))  unsigned int;

#define AS1 __attribute__((address_space(1)))
#define AS3 __attribute__((address_space(3)))

__device__ __forceinline__ unsigned short f2bf(float f) {
  union { float f; unsigned int u; } v; v.f = f;
  unsigned int r = v.u + 0x7FFFu + ((v.u >> 16) & 1u);
  return (unsigned short)(r >> 16);
}
__device__ __forceinline__ void gload_lds16(const void* g, void* l) {
  __builtin_amdgcn_global_load_lds((const AS1 unsigned int*)g, (AS3 unsigned int*)l, 16, 0, 0);
}

#define B_  16
#define L_  4096
#define E_  128
#define F_  256
#define Y_  1000

// workspace offsets (bytes)
#define OFF_HLF   0u          // B*L*F bf16 = 32 MB (l,f) rows of 512B
#define OFF_UBF   33554432u   // 1024*256 bf16 (U padded, pre-scaled by log2e)
#define OFF_FBF   34078720u   // 1024*256 bf16 (fc_w padded)
#define OFF_WBF   34603008u   // 3*256*128 bf16
#define OFF_PART  34799616u   // 16*8*8*128 float2 = 1 MB

// ---------------- K0: all repacks in one launch + zero the loss slot --------
// U is pre-scaled by log2(e): S' = S*log2e -> p = exp2(S') = exp(S), one v_exp.
__global__ __launch_bounds__(256) void k_repack(const float* __restrict__ Uw,
                                                const float* __restrict__ fcw,
                                                const float* __restrict__ cw,
                                                unsigned short* __restrict__ ubf,
                                                unsigned short* __restrict__ fbf,
                                                unsigned short* __restrict__ wbf,
                                                float* __restrict__ out) {
  const int bid = blockIdx.x, tid = threadIdx.x;
  if (bid == 0 && tid == 0) out[B_ * Y_] = 0.f;   // loss accumulator
  if (bid < 2048) {
    const float* src = (bid < 1024) ? Uw : fcw;
    const float scale = (bid < 1024) ? 1.44269504089f : 1.f;
    unsigned short* dst = (bid < 1024) ? ubf : fbf;
    int i = (bid & 1023) * 256 + tid;
    int y = i >> 8, f = i & 255;
    float v = (y < Y_) ? src[y * F_ + f] * scale : 0.f;
    dst[i] = f2bf(v);
  } else {
    int i = (bid - 2048) * 256 + tid;   // 32768 = 256*128
    const float* s = cw + (size_t)i * 3;
    wbf[0 * 32768 + i] = f2bf(s[0]);
    wbf[1 * 32768 + i] = f2bf(s[1]);
    wbf[2 * 32768 + i] = f2bf(s[2]);
  }
}

// ---------------- K1: fused embed-gather + conv1d(K=3,SAME) + bias + relu ----
// (byte-identical to r8 -- known-stable; isolating the attn experiment)
#define ET_STR 272
__global__ __launch_bounds__(256, 2) void k_conv(const unsigned short* __restrict__ wbf,
                                                 const float* __restrict__ conv_b,
                                                 const int* __restrict__ x,
                                                 const float* __restrict__ ew,
                                                 unsigned short* __restrict__ hlf) {
  __shared__ unsigned char et[66 * ET_STR];  // 17952
  const int tid = threadIdx.x, bid = blockIdx.x;
  const int b = bid >> 6, l0 = (bid & 63) << 6;
  const int w = tid >> 6, lane = tid & 63, c = lane & 15, q = lane >> 4;
  const int* xb = x + b * L_;
  for (int s = tid; s < 1056; s += 256) {
    int row = s >> 4, sg = s & 15;
    int l = l0 - 1 + row;
    int idx = (l >= 0 && l < L_) ? xb[l] : 0;
    const float4* src = (const float4*)(ew + (size_t)idx * E_ + sg * 8);
    float4 a = src[0], bb = src[1];
    uintx4 v;
    v.x = (unsigned int)f2bf(a.x) | ((unsigned int)f2bf(a.y) << 16);
    v.y = (unsigned int)f2bf(a.z) | ((unsigned int)f2bf(a.w) << 16);
    v.z = (unsigned int)f2bf(bb.x) | ((unsigned int)f2bf(bb.y) << 16);
    v.w = (unsigned int)f2bf(bb.z) | ((unsigned int)f2bf(bb.w) << 16);
    *(uintx4*)(et + row * ET_STR + sg * 16) = v;
  }
  __syncthreads();
  const int fw = w * 64;
  floatx4 acc[4][4];
  #pragma unroll
  for (int ms = 0; ms < 4; ++ms)
    #pragma unroll
    for (int nt = 0; nt < 4; ++nt) acc[ms][nt] = (floatx4){0.f, 0.f, 0.f, 0.f};
  #pragma unroll
  for (int d = 0; d < 3; ++d)
    #pragma unroll
    for (int kq = 0; kq < 4; ++kq) {
      short8 aa[4], bb[4];
      #pragma unroll
      for (int ms = 0; ms < 4; ++ms)
        aa[ms] = *(const short8*)(et + (ms * 16 + c + d) * ET_STR + kq * 64 + q * 16);
      #pragma unroll
      for (int nt = 0; nt < 4; ++nt)
        bb[nt] = *(const short8*)((const unsigned char*)wbf +
                   ((size_t)(d * F_ + fw + nt * 16 + c) * E_ + kq * 32 + q * 8) * 2);
      #pragma unroll
      for (int ms = 0; ms < 4; ++ms)
        #pragma unroll
        for (int nt = 0; nt < 4; ++nt)
          acc[ms][nt] = __builtin_amdgcn_mfma_f32_16x16x32_bf16(aa[ms], bb[nt], acc[ms][nt], 0, 0, 0);
    }
  #pragma unroll
  for (int nt = 0; nt < 4; ++nt) {
    int f = fw + nt * 16 + c;
    float bias = conv_b[f];
    #pragma unroll
    for (int ms = 0; ms < 4; ++ms)
      #pragma unroll
      for (int r = 0; r < 4; ++r) {
        int l = l0 + ms * 16 + q * 4 + r;
        float v = acc[ms][nt][r] + bias;
        v = v > 0.f ? v : 0.f;
        hlf[((size_t)b * L_ + l) * F_ + f] = f2bf(v);
      }
  }
}

// ---------------- K2: fused attention, register-dieted for 3 waves/SIMD ------
// uf resident (64 VGPR); ff STREAMED from L2 each iter (opaque-ptr asm defeats
// loop-invariant hoisting) -> total regs ~160 <= 170 cap of launch_bounds(256,3).
// grid 1024 = 16b x 8yt(128y) x 8chunks(512 l) -> 3 wg/CU resident (LDS 96KB).
__global__ __launch_bounds__(256, 3) void k_attn(const unsigned short* __restrict__ ubf,
                                                 const unsigned short* __restrict__ fbf,
                                                 const unsigned short* __restrict__ hlf,
                                                 float2* __restrict__ part) {
  __shared__ unsigned char lds[32768];
  const int tid = threadIdx.x;
  const int w = tid >> 6, lane = tid & 63, lo = lane & 31, hi = lane >> 5;
  const int bid = blockIdx.x;
  const int xcd = bid & 7, r0 = bid >> 3;
  const int b = xcd * 2 + (r0 & 1);               // 2 batches per XCD L2
  const int r2 = r0 >> 1, yt = r2 & 7, chunk = r2 >> 3;
  const int y0 = yt << 7, yw = y0 + w * 32;
  const unsigned char* hlfb = (const unsigned char*)hlf + (size_t)b * L_ * (F_ * 2);
  const int l0base = chunk << 9;

#define STAGE(dstbuf, l0v)                                                      \
  {                                                                             \
    unsigned char* dstb = (dstbuf);                                             \
    _Pragma("unroll")                                                           \
    for (int ii = 0; ii < 4; ++ii) {                                            \
      int i = w * 4 + ii;                                                       \
      int r = 2 * i + hi;                                                       \
      int g = lo ^ r;                                                           \
      gload_lds16(hlfb + (size_t)((l0v) + r) * 512 + g * 16, dstb + i * 1024);  \
    }                                                                           \
  }

  STAGE(lds, l0base);
  // U A-frags resident (wave's 32 y, K=256 -> 16 ks); loaded while stage flies
  short8 uf[16];
  #pragma unroll
  for (int ks = 0; ks < 16; ++ks)
    uf[ks] = *(const short8*)((const unsigned char*)ubf +
               ((size_t)(yw + lo) * F_ + ks * 16 + hi * 8) * 2);
  // per-lane streamed-Fc pointer (made opaque each iter)
  const unsigned char* fptr = (const unsigned char*)fbf +
                              ((size_t)(yw + lo) * F_ + hi * 8) * 2;
  float num[16], den[16];
  #pragma unroll
  for (int r = 0; r < 16; ++r) { num[r] = 0.f; den[r] = 0.f; }
  __syncthreads();
  for (int it = 0; it < 16; ++it) {
    unsigned char* cur = lds + ((it & 1) << 14);
    if (it < 15) STAGE(lds + (((it & 1) ^ 1) << 14), l0base + (it + 1) * 32);
    asm volatile("" : "+v"(fptr));   // break loop-invariance: force per-iter reload
    floatx16 S = {0.f,0.f,0.f,0.f,0.f,0.f,0.f,0.f,0.f,0.f,0.f,0.f,0.f,0.f,0.f,0.f};
    floatx16 G = S;
    #pragma unroll
    for (int ks = 0; ks < 16; ++ks) {
      short8 bb = *(const short8*)(cur + lo * 512 + (((ks * 2 + hi) ^ lo) << 4));
      S = __builtin_amdgcn_mfma_f32_32x32x16_bf16(uf[ks], bb, S, 0, 0, 0);
      short8 ffk = *(const short8*)(fptr + ks * 32);
      G = __builtin_amdgcn_mfma_f32_32x32x16_bf16(ffk, bb, G, 0, 0, 0);
    }
    #pragma unroll
    for (int r = 0; r < 16; ++r) {
      float p = exp2f(S[r]);         // U pre-scaled by log2e -> p = exp(S_true)
      num[r] = fmaf(p, G[r], num[r]);
      den[r] += p;
    }
    __syncthreads();
  }
  // reduce over the 32 l-columns
  #pragma unroll
  for (int r = 0; r < 16; ++r) {
    float n = num[r], d = den[r];
    n += __shfl_xor(n, 1, 64);  d += __shfl_xor(d, 1, 64);
    n += __shfl_xor(n, 2, 64);  d += __shfl_xor(d, 2, 64);
    n += __shfl_xor(n, 4, 64);  d += __shfl_xor(d, 4, 64);
    n += __shfl_xor(n, 8, 64);  d += __shfl_xor(d, 8, 64);
    n += __shfl_xor(n, 16, 64); d += __shfl_xor(d, 16, 64);
    num[r] = n; den[r] = d;
  }
  float2* pb = part + (size_t)((b * 8 + yt) * 8 + chunk) * 128;
  if (lo == 0) {
    #pragma unroll
    for (int r = 0; r < 16; ++r) {
      int yl = w * 32 + (r & 3) + 8 * (r >> 2) + 4 * hi;  // 32x32 C/D row mapping
      float2 v; v.x = num[r]; v.y = den[r];
      pb[yl] = v;
    }
  }
}

// ---------------- K3: combine partials -> logits + CE loss (atomic mean) ----
__global__ __launch_bounds__(256) void k_logits(const float2* __restrict__ part,
                                                const float* __restrict__ fcb,
                                                const int* __restrict__ target,
                                                float* __restrict__ out) {
  __shared__ float red[4];
  const int b = blockIdx.x, tid = threadIdx.x;
  const int w = tid >> 6;
  float lg[4];
  #pragma unroll
  for (int k = 0; k < 4; ++k) {
    int y = tid + k * 256;
    int yt = y >> 7, yl = y & 127;
    float n = 0.f, la = 0.f;
    #pragma unroll
    for (int ch = 0; ch < 8; ++ch) {
      float2 v = part[(size_t)((b * 8 + yt) * 8 + ch) * 128 + yl];
      n += v.x; la += v.y;
    }
    float lv = (y < Y_) ? (n / la + fcb[y]) : -1e30f;
    lg[k] = lv;
    if (y < Y_) out[b * Y_ + y] = lv;
  }
  float m = fmaxf(fmaxf(lg[0], lg[1]), fmaxf(lg[2], lg[3]));
  for (int off = 1; off < 64; off <<= 1) m = fmaxf(m, __shfl_xor(m, off, 64));
  if ((tid & 63) == 0) red[w] = m;
  __syncthreads();
  m = fmaxf(fmaxf(red[0], red[1]), fmaxf(red[2], red[3]));
  __syncthreads();
  float s = 0.f;
  #pragma unroll
  for (int k = 0; k < 4; ++k)
    if (tid + k * 256 < Y_) s += __expf(lg[k] - m);
  for (int off = 1; off < 64; off <<= 1) s += __shfl_xor(s, off, 64);
  if ((tid & 63) == 0) red[w] = s;
  __syncthreads();
  s = red[0] + red[1] + red[2] + red[3];
  int t = target[b];
  #pragma unroll
  for (int k = 0; k < 4; ++k)
    if (tid + k * 256 == t)
      atomicAdd(&out[B_ * Y_], -(lg[k] - m - logf(s)) * (1.f / (float)B_));
}

// ---------------- launcher ----------------
extern "C" void kernel_launch(void* const* d_in, const int* in_sizes, int n_in,
                              void* d_out, int out_size, void* d_ws, size_t ws_size,
                              hipStream_t stream) {
  const int*   x       = (const int*)d_in[0];
  const int*   target  = (const int*)d_in[1];
  const float* embed_w = (const float*)d_in[2];
  const float* conv_w  = (const float*)d_in[3];
  const float* conv_b  = (const float*)d_in[4];
  const float* U_w     = (const float*)d_in[5];
  const float* fc_w    = (const float*)d_in[6];
  const float* fc_b    = (const float*)d_in[7];
  float* out = (float*)d_out;
  unsigned char* ws = (unsigned char*)d_ws;
  unsigned short* hlf  = (unsigned short*)(ws + OFF_HLF);
  unsigned short* ubf  = (unsigned short*)(ws + OFF_UBF);
  unsigned short* fbf  = (unsigned short*)(ws + OFF_FBF);
  unsigned short* wbf  = (unsigned short*)(ws + OFF_WBF);
  float2*         part = (float2*)(ws + OFF_PART);

  k_repack<<<2176, 256, 0, stream>>>(U_w, fc_w, conv_w, ubf, fbf, wbf, out);
  k_conv<<<1024, 256, 0, stream>>>(wbf, conv_b, x, embed_w, hlf);
  k_attn<<<1024, 256, 0, stream>>>(ubf, fbf, hlf, part);
  k_logits<<<16, 256, 0, stream>>>(part, fc_b, target, out);
}

// Round 10
// 243.807 us; speedup vs baseline: 1.2000x; 1.2000x over previous
//
#include <hip/hip_runtime.h>
#include <math.h>

using short8   = __attribute__((ext_vector_type(8)))  short;
using floatx4  = __attribute__((ext_vector_type(4)))  float;
using floatx16 = __attribute__((ext_vector_type(16))) float;
using uintx4   = __attribute__((ext_vector_type(4)))  unsigned int;

#define AS1 __attribute__((address_space(1)))
#define AS3 __attribute__((address_space(3)))

__device__ __forceinline__ unsigned short f2bf(float f) {
  union { float f; unsigned int u; } v; v.f = f;
  unsigned int r = v.u + 0x7FFFu + ((v.u >> 16) & 1u);
  return (unsigned short)(r >> 16);
}
__device__ __forceinline__ void gload_lds16(const void* g, void* l) {
  __builtin_amdgcn_global_load_lds((const AS1 unsigned int*)g, (AS3 unsigned int*)l, 16, 0, 0);
}

#define B_  16
#define L_  4096
#define E_  128
#define F_  256
#define Y_  1000

// workspace offsets (bytes)
#define OFF_HLF   0u          // B*L*F bf16 = 32 MB (l,f) rows of 512B
#define OFF_WBF   33554432u   // 3*256*128 bf16
#define OFF_PART  33751040u   // 16*8*4*128 float2 = 512 KB

// ---------------- K0: repack conv_w (F,E,K) fp32 -> bf16 [d][f][e] ----------
__global__ __launch_bounds__(256) void k_repack_w(const float* __restrict__ cw,
                                                  unsigned short* __restrict__ wbf) {
  int i = blockIdx.x * 256 + threadIdx.x;   // 32768 = 256*128
  const float* s = cw + (size_t)i * 3;
  wbf[0 * 32768 + i] = f2bf(s[0]);
  wbf[1 * 32768 + i] = f2bf(s[1]);
  wbf[2 * 32768 + i] = f2bf(s[2]);
}

// ---------------- K1: fused embed-gather + conv1d(K=3,SAME) + bias + relu ----
// grid 1024 = 16b x 64 lgroups(64 l). r5-proven gather+MFMA body; NEW epilogue:
// acc -> LDS (union with emb tile) -> coalesced b128 stores (8 insts/thread
// instead of 64 global_store_short scattering 32-B segments).
#define ET_STR 272
__global__ __launch_bounds__(256, 2) void k_conv(const unsigned short* __restrict__ wbf,
                                                 const float* __restrict__ conv_b,
                                                 const int* __restrict__ x,
                                                 const float* __restrict__ ew,
                                                 unsigned short* __restrict__ hlf) {
  __shared__ unsigned char lds[32768];       // et (17952) then reused as tl (32768)
  unsigned char* et = lds;
  const int tid = threadIdx.x, bid = blockIdx.x;
  const int b = bid >> 6, l0 = (bid & 63) << 6;
  const int w = tid >> 6, lane = tid & 63, c = lane & 15, q = lane >> 4;
  const int* xb = x + b * L_;
  // gather + fp32->bf16 convert emb halo tile (66 rows x 128 e)
  for (int s = tid; s < 1056; s += 256) {
    int row = s >> 4, sg = s & 15;
    int l = l0 - 1 + row;
    int idx = (l >= 0 && l < L_) ? xb[l] : 0;
    const float4* src = (const float4*)(ew + (size_t)idx * E_ + sg * 8);
    float4 a = src[0], bb = src[1];
    uintx4 v;
    v.x = (unsigned int)f2bf(a.x) | ((unsigned int)f2bf(a.y) << 16);
    v.y = (unsigned int)f2bf(a.z) | ((unsigned int)f2bf(a.w) << 16);
    v.z = (unsigned int)f2bf(bb.x) | ((unsigned int)f2bf(bb.y) << 16);
    v.w = (unsigned int)f2bf(bb.z) | ((unsigned int)f2bf(bb.w) << 16);
    *(uintx4*)(et + row * ET_STR + sg * 16) = v;
  }
  __syncthreads();
  const int fw = w * 64;
  floatx4 acc[4][4];
  #pragma unroll
  for (int ms = 0; ms < 4; ++ms)
    #pragma unroll
    for (int nt = 0; nt < 4; ++nt) acc[ms][nt] = (floatx4){0.f, 0.f, 0.f, 0.f};
  #pragma unroll
  for (int d = 0; d < 3; ++d)
    #pragma unroll
    for (int kq = 0; kq < 4; ++kq) {
      short8 aa[4], bb[4];
      #pragma unroll
      for (int ms = 0; ms < 4; ++ms)
        aa[ms] = *(const short8*)(et + (ms * 16 + c + d) * ET_STR + kq * 64 + q * 16);
      #pragma unroll
      for (int nt = 0; nt < 4; ++nt)
        bb[nt] = *(const short8*)((const unsigned char*)wbf +
                   ((size_t)(d * F_ + fw + nt * 16 + c) * E_ + kq * 32 + q * 8) * 2);
      #pragma unroll
      for (int ms = 0; ms < 4; ++ms)
        #pragma unroll
        for (int nt = 0; nt < 4; ++nt)
          acc[ms][nt] = __builtin_amdgcn_mfma_f32_16x16x32_bf16(aa[ms], bb[nt], acc[ms][nt], 0, 0, 0);
    }
  __syncthreads();                 // et dead; reuse LDS as tl [64 l][512 B f]
  unsigned char* tl = lds;
  #pragma unroll
  for (int nt = 0; nt < 4; ++nt) {
    int f = fw + nt * 16 + c;
    float bias = conv_b[f];
    #pragma unroll
    for (int ms = 0; ms < 4; ++ms)
      #pragma unroll
      for (int r = 0; r < 4; ++r) {
        float v = acc[ms][nt][r] + bias;
        v = v > 0.f ? v : 0.f;
        *(unsigned short*)(tl + (ms * 16 + q * 4 + r) * 512 + f * 2) = f2bf(v);
      }
  }
  __syncthreads();
  // coalesced b128 stores: 64 rows x 512 B
  unsigned char* hb = (unsigned char*)hlf + ((size_t)b * L_ + l0) * (F_ * 2);
  for (int s = tid; s < 2048; s += 256) {
    int row = s >> 5, sg = s & 31;
    *(uintx4*)(hb + (size_t)row * 512 + sg * 16) = *(const uintx4*)(tl + row * 512 + sg * 16);
  }
}

// ---------------- K2: fused attention (EXACT r5 inner loop, 71.2 us proven) --
// grid 512 = 16b x 8yt(128y) x 4chunks(1024 l). (256,2), Tl=32, dbuf 2x16KB.
// NEW: prologue self-converts U/fc from fp32 (kills the 2048-block repack);
// y>=1000 rows -> zero frags (same semantics as the old zero-padded tables).
__global__ __launch_bounds__(256, 2) void k_attn(const float* __restrict__ Uw,
                                                 const float* __restrict__ Fw,
                                                 const unsigned short* __restrict__ hlf,
                                                 float2* __restrict__ part) {
  __shared__ unsigned char lds[32768];
  const int tid = threadIdx.x;
  const int w = tid >> 6, lane = tid & 63, lo = lane & 31, hi = lane >> 5;
  const int bid = blockIdx.x;
  const int xcd = bid & 7, r0 = bid >> 3;
  const int b = xcd * 2 + (r0 & 1);               // 2 batches per XCD L2
  const int r2 = r0 >> 1, yt = r2 & 7, chunk = r2 >> 3;
  const int y0 = yt << 7, yw = y0 + w * 32;
  const unsigned char* hlfb = (const unsigned char*)hlf + (size_t)b * L_ * (F_ * 2);
  const int l0base = chunk << 10;

#define STAGE(dstbuf, l0v)                                                      \
  {                                                                             \
    unsigned char* dstb = (dstbuf);                                             \
    _Pragma("unroll")                                                           \
    for (int ii = 0; ii < 4; ++ii) {                                            \
      int i = w * 4 + ii;                                                       \
      int r = 2 * i + hi;                                                       \
      int g = lo ^ r;                                                           \
      gload_lds16(hlfb + (size_t)((l0v) + r) * 512 + g * 16, dstb + i * 1024);  \
    }                                                                           \
  }

  STAGE(lds, l0base);
  // self-converting A-frag prologue (fp32 -> bf16, RNE: identical to old repack)
  const int ya = yw + lo;
  const bool yv = (ya < Y_);
  const float* up = Uw + (size_t)(yv ? ya : 0) * F_;
  const float* fp = Fw + (size_t)(yv ? ya : 0) * F_;
  short8 uf[16], ff[16];
  #pragma unroll
  for (int ks = 0; ks < 16; ++ks) {
    short8 u, f;
    #pragma unroll
    for (int j = 0; j < 8; ++j) {
      float uvv = yv ? up[ks * 16 + hi * 8 + j] : 0.f;
      float fvv = yv ? fp[ks * 16 + hi * 8 + j] : 0.f;
      u[j] = (short)f2bf(uvv);
      f[j] = (short)f2bf(fvv);
    }
    uf[ks] = u; ff[ks] = f;
  }
  float num[16], den[16];
  #pragma unroll
  for (int r = 0; r < 16; ++r) { num[r] = 0.f; den[r] = 0.f; }
  __syncthreads();
  for (int it = 0; it < 32; ++it) {
    unsigned char* cur = lds + ((it & 1) << 14);
    if (it < 31) STAGE(lds + (((it & 1) ^ 1) << 14), l0base + (it + 1) * 32);
    floatx16 S = {0.f,0.f,0.f,0.f,0.f,0.f,0.f,0.f,0.f,0.f,0.f,0.f,0.f,0.f,0.f,0.f};
    floatx16 G = S;
    #pragma unroll
    for (int ks = 0; ks < 16; ++ks) {
      short8 bb = *(const short8*)(cur + lo * 512 + (((ks * 2 + hi) ^ lo) << 4));
      S = __builtin_amdgcn_mfma_f32_32x32x16_bf16(uf[ks], bb, S, 0, 0, 0);
      G = __builtin_amdgcn_mfma_f32_32x32x16_bf16(ff[ks], bb, G, 0, 0, 0);
    }
    #pragma unroll
    for (int r = 0; r < 16; ++r) {
      float p = __expf(S[r]);
      num[r] += p * G[r];
      den[r] += p;
    }
    __syncthreads();
  }
  #pragma unroll
  for (int r = 0; r < 16; ++r) {
    float n = num[r], d = den[r];
    n += __shfl_xor(n, 1, 64);  d += __shfl_xor(d, 1, 64);
    n += __shfl_xor(n, 2, 64);  d += __shfl_xor(d, 2, 64);
    n += __shfl_xor(n, 4, 64);  d += __shfl_xor(d, 4, 64);
    n += __shfl_xor(n, 8, 64);  d += __shfl_xor(d, 8, 64);
    n += __shfl_xor(n, 16, 64); d += __shfl_xor(d, 16, 64);
    num[r] = n; den[r] = d;
  }
  float2* pb = part + (size_t)((b * 8 + yt) * 4 + chunk) * 128;
  if (lo == 0) {
    #pragma unroll
    for (int r = 0; r < 16; ++r) {
      int yl = w * 32 + (r & 3) + 8 * (r >> 2) + 4 * hi;  // 32x32 C/D row mapping
      float2 v; v.x = num[r]; v.y = den[r];
      pb[yl] = v;
    }
  }
}

// ---------------- K3: ONE block, wave-per-batch: logits + CE loss -----------
// 16 waves = 16 batches; per-wave softmax (no cross-wave barriers for it);
// no atomics, no zero-init dependency.
__global__ __launch_bounds__(1024) void k_logits(const float2* __restrict__ part,
                                                 const float* __restrict__ fcb,
                                                 const int* __restrict__ target,
                                                 float* __restrict__ out) {
  __shared__ float wloss[16];
  const int tid = threadIdx.x, w = tid >> 6, lane = tid & 63;
  const int b = w, t = target[b];
  float lg[16];
  float m = -1e30f;
  #pragma unroll
  for (int j = 0; j < 16; ++j) {
    int y = lane + j * 64;
    int yt = y >> 7, yl = y & 127;
    float n = 0.f, la = 0.f;
    #pragma unroll
    for (int ch = 0; ch < 4; ++ch) {
      float2 v = part[(size_t)((b * 8 + yt) * 4 + ch) * 128 + yl];
      n += v.x; la += v.y;
    }
    float lv = (y < Y_) ? (n / la + fcb[y]) : -1e30f;
    lg[j] = lv;
    m = fmaxf(m, lv);
    if (y < Y_) out[b * Y_ + y] = lv;
  }
  for (int off = 1; off < 64; off <<= 1) m = fmaxf(m, __shfl_xor(m, off, 64));
  float s = 0.f, lt = 0.f;
  #pragma unroll
  for (int j = 0; j < 16; ++j) {
    int y = lane + j * 64;
    if (y < Y_) s += __expf(lg[j] - m);
    if (y == t) lt = lg[j];
  }
  for (int off = 1; off < 64; off <<= 1) {
    s += __shfl_xor(s, off, 64);
    lt += __shfl_xor(lt, off, 64);
  }
  if (lane == 0) wloss[w] = -(lt - m - logf(s));
  __syncthreads();
  if (tid == 0) {
    float acc = 0.f;
    #pragma unroll
    for (int i = 0; i < 16; ++i) acc += wloss[i];
    out[B_ * Y_] = acc * (1.f / (float)B_);
  }
}

// ---------------- launcher ----------------
extern "C" void kernel_launch(void* const* d_in, const int* in_sizes, int n_in,
                              void* d_out, int out_size, void* d_ws, size_t ws_size,
                              hipStream_t stream) {
  const int*   x       = (const int*)d_in[0];
  const int*   target  = (const int*)d_in[1];
  const float* embed_w = (const float*)d_in[2];
  const float* conv_w  = (const float*)d_in[3];
  const float* conv_b  = (const float*)d_in[4];
  const float* U_w     = (const float*)d_in[5];
  const float* fc_w    = (const float*)d_in[6];
  const float* fc_b    = (const float*)d_in[7];
  float* out = (float*)d_out;
  unsigned char* ws = (unsigned char*)d_ws;
  unsigned short* hlf  = (unsigned short*)(ws + OFF_HLF);
  unsigned short* wbf  = (unsigned short*)(ws + OFF_WBF);
  float2*         part = (float2*)(ws + OFF_PART);

  k_repack_w<<<128, 256, 0, stream>>>(conv_w, wbf);
  k_conv<<<1024, 256, 0, stream>>>(wbf, conv_b, x, embed_w, hlf);
  k_attn<<<512, 256, 0, stream>>>(U_w, fc_w, hlf, part);
  k_logits<<<1, 1024, 0, stream>>>(part, fc_b, target, out);
}